// Round 1
// baseline (372.598 us; speedup 1.0000x reference)
//
#include <hip/hip_runtime.h>
#include <stdint.h>
#include <limits.h>

// Problem constants (reference: B=4, N=8192, C=64, OUT=64, KNN=36)
#define BB 4
#define NN 8192
#define CC 64
#define OUTD 64
#define KK 36
#define NPTS (BB * NN)          // 32768
#define NBIN 129                // bins 0..128 (0 and 128 are clamp catch-alls)
// t = signed(float_bits(d2)) >> 20 (arith); bin = med3_i32(t,960,1088) - 960.
// Negative d2 (fp rounding) -> t very negative -> bin 0. One integer t per bin.
//
// xyzw layout: PAIR-INTERLEAVED. For even j: 8 floats
//   [x_j, x_j1, y_j, y_j1, z_j, z_j1, w_j, w_j1]   (j1 = j+1; 32 B per pair)

typedef float v2f __attribute__((ext_vector_type(2)));
typedef float v4f __attribute__((ext_vector_type(4)));

static __device__ __forceinline__ int laneid() { return threadIdx.x & 63; }
static __device__ __forceinline__ int waveid_uniform() {
    return __builtin_amdgcn_readfirstlane((int)(threadIdx.x >> 6));
}
static __device__ __forceinline__ float rdlane_f(float v, int l) {
    return __int_as_float(__builtin_amdgcn_readlane(__float_as_int(v), l));
}
// DPP helper: VALU-pipe cross-lane (no LDS). ctrl/bound must be constants.
#define DPP_F(oldv, v, ctrl, bound) \
    __int_as_float(__builtin_amdgcn_update_dpp( \
        __float_as_int(oldv), __float_as_int(v), (ctrl), 0xf, 0xf, (bound)))

// 64-lane sum: result in lane 63 (row_shr prefix + row_bcast combine)
static __device__ __forceinline__ float wave_sum_dpp(float v) {
    v += DPP_F(0.0f, v, 0x111, true);   // row_shr:1
    v += DPP_F(0.0f, v, 0x112, true);   // row_shr:2
    v += DPP_F(0.0f, v, 0x114, true);   // row_shr:4
    v += DPP_F(0.0f, v, 0x118, true);   // row_shr:8
    v += DPP_F(0.0f, v, 0x142, true);   // row_bcast:15
    v += DPP_F(0.0f, v, 0x143, true);   // row_bcast:31
    return rdlane_f(v, 63);
}
// 64-lane max: OOB lanes keep old=v (no-op under max)
static __device__ __forceinline__ float wave_max_dpp(float v) {
    v = fmaxf(v, DPP_F(v, v, 0x111, false));
    v = fmaxf(v, DPP_F(v, v, 0x112, false));
    v = fmaxf(v, DPP_F(v, v, 0x114, false));
    v = fmaxf(v, DPP_F(v, v, 0x118, false));
    v = fmaxf(v, DPP_F(v, v, 0x142, false));
    v = fmaxf(v, DPP_F(v, v, 0x143, false));
    return rdlane_f(v, 63);
}

// ---------------------------------------------------------------------------
// Kernel 1: v_feat = relu([feature, xyz] @ W_v + b_v)  + pair-interleaved xyzw.
// One wave handles 8 points. Block = 256 = 4 waves. grid = NPTS/32.
// ---------------------------------------------------------------------------
__global__ __launch_bounds__(256) void k_vfeat(
    const float* __restrict__ feat, const float* __restrict__ xyz,
    const float* __restrict__ Wv, const float* __restrict__ bv,
    float* __restrict__ vfeat, float* __restrict__ xp)   // xp: interleaved xyzw
{
    __shared__ float fb[4][8][64];
    __shared__ float xb[4][8][3];
    const int lane = laneid();
    const int wv = waveid_uniform();
    const int pbase = blockIdx.x * 32 + wv * 8;

    #pragma unroll
    for (int pp = 0; pp < 8; ++pp)
        fb[wv][pp][lane] = feat[(pbase + pp) * CC + lane];
    if (lane < 24)
        xb[wv][lane / 3][lane % 3] = xyz[pbase * 3 + lane];
    // same-wave LDS write->read: in-order per wave, compiler inserts lgkmcnt

    const float b0 = bv[lane];
    float acc[8];
    #pragma unroll
    for (int pp = 0; pp < 8; ++pp) acc[pp] = b0;

    #pragma unroll 4
    for (int c = 0; c < CC; ++c) {
        float w = Wv[c * OUTD + lane];
        #pragma unroll
        for (int pp = 0; pp < 8; ++pp)
            acc[pp] = fmaf(fb[wv][pp][c], w, acc[pp]);
    }
    const float wx = Wv[64 * OUTD + lane];
    const float wy = Wv[65 * OUTD + lane];
    const float wz = Wv[66 * OUTD + lane];
    #pragma unroll
    for (int pp = 0; pp < 8; ++pp) {
        float a = acc[pp];
        a = fmaf(xb[wv][pp][0], wx, a);
        a = fmaf(xb[wv][pp][1], wy, a);
        a = fmaf(xb[wv][pp][2], wz, a);
        vfeat[(pbase + pp) * OUTD + lane] = fmaxf(a, 0.0f);
    }
    if (lane < 8) {
        const int p = pbase + lane;
        const float x = xb[wv][lane][0], y = xb[wv][lane][1], z = xb[wv][lane][2];
        const float sq = (x * x + y * y) + z * z;
        const int base = (p >> 1) * 8 + (p & 1);    // pair-interleaved slot
        xp[base + 0] = x;
        xp[base + 2] = y;
        xp[base + 4] = z;
        xp[base + 6] = sq;
    }
}

// ---------------------------------------------------------------------------
// Kernel 2: 36-NN via per-query float-bit histogram selection.
// 512 blocks x 1024 thr, 64 queries/block (lane-per-query), 2 blocks/CU.
//
// V2 structure: candidate tiles are fetched with per-lane VMEM broadcast
// loads (all 64 lanes same address -> single-line broadcast) instead of
// wave-uniform s_load. Rationale: SMEM returns complete OUT-OF-ORDER within
// lgkmcnt, so consuming an s_load forces lgkmcnt(0), which also drains the
// in-flight ds_add histogram atomics (DS and SMEM share lgkmcnt) -> per-group
// convoy. VMEM returns are in-order under vmcnt and fully decoupled from the
// DS queue; a manual 2-stage register double-buffer gives 1-body prefetch
// distance (8 waves/SIMD then cover L2 latency).
//
// Pass 2 thresholds are evaluated in the BITS domain (no per-candidate ashr):
//   t <= TH  <=>  bits <= ((TH+1)<<20)-1      (arith-shift monotone)
//   t <  TL  <=>  bits <  (TL<<20)
// Exact key fmaxf(d,0) bits == max(bits,0) as int. Bit-identical semantics.
// ---------------------------------------------------------------------------
__global__ __launch_bounds__(1024, 8) void k_knn(
    const float* __restrict__ xpAll, int* __restrict__ idx_ws)
{
    __shared__ __align__(16) uint32_t hist[NBIN * 64];  // 33 KB; reused as buf in pass 2
    __shared__ int binB[64];
    __shared__ int cumLoA[64];
    __shared__ uint32_t bufCnt[64];
    __shared__ uint32_t dirCnt[64];

    const int lane = laneid();
    const int wv = waveid_uniform();               // 0..15
    const int batch = blockIdx.x >> 7;             // 128 blocks per batch
    const int qbase = (blockIdx.x & 127) << 6;
    const int q = qbase + lane;                    // local query id 0..8191
    const float* __restrict__ xp = xpAll + (size_t)batch * NN * 4;

    // per-lane query fetch from the interleaved layout (once per block)
    const int pr = q >> 1, sub = q & 1;
    const float Qx = xp[pr * 8 + sub + 0];
    const float Qy = xp[pr * 8 + sub + 2];
    const float Qz = xp[pr * 8 + sub + 4];
    const float Qw = xp[pr * 8 + sub + 6];
    const v2f qx = { Qx, Qx };
    const v2f qy = { Qy, Qy };
    const v2f qz = { Qz, Qz };
    const v2f qw = { Qw, Qw };
    const v2f m2 = { -2.0f, -2.0f };

    const int h0 = wv * 256;                       // pair-index base (512 cands)
    const int laneAdj = lane - 960 * 64;           // fold bin rebase into addressing

    // divergent zero: defeats the scalarizer so candidate loads stay VMEM
    // (global_load_dwordx4 broadcast), keeping their waits on vmcnt and out
    // of the shared lgkm counter the ds_add atomics live on.
    const int zd = (int)__builtin_amdgcn_mbcnt_lo(0u, 0u);
    const char* candBase = (const char*)xp + (size_t)h0 * 32 + zd;

    for (int i = threadIdx.x; i < NBIN * 64; i += 1024) hist[i] = 0u;
    if (threadIdx.x < 64) { bufCnt[threadIdx.x] = 0u; dirCnt[threadIdx.x] = 0u; }
    __syncthreads();

// 64 B group = 2 pairs = 4 candidates, one cache line, 4x dwordx4 broadcast
#define LOADG(d0, d1, d2_, d3_, byteoff) do { \
        const v4f* _p = (const v4f*)(candBase + (byteoff)); \
        d0 = _p[0]; d1 = _p[1]; d2_ = _p[2]; d3_ = _p[3]; } while (0)

// shared distance math for one 2-pair group (identical op sequence in both
// passes -> identical bits -> histogram/selection consistency)
#define DISTS(A0, A1, A2, A3) \
        v2f cx0 = { A0.x, A0.y }, cy0 = { A0.z, A0.w }; \
        v2f cz0 = { A1.x, A1.y }, cw0 = { A1.z, A1.w }; \
        v2f cx1 = { A2.x, A2.y }, cy1 = { A2.z, A2.w }; \
        v2f cz1 = { A3.x, A3.y }, cw1 = { A3.z, A3.w }; \
        v2f dot0 = __builtin_elementwise_fma(qx, cx0, \
                   __builtin_elementwise_fma(qy, cy0, qz * cz0)); \
        v2f d20  = __builtin_elementwise_fma(m2, dot0, qw + cw0); \
        v2f dot1 = __builtin_elementwise_fma(qx, cx1, \
                   __builtin_elementwise_fma(qy, cy1, qz * cz1)); \
        v2f d21  = __builtin_elementwise_fma(m2, dot1, qw + cw1);

#define P1BODY(A0, A1, A2, A3) do { \
        DISTS(A0, A1, A2, A3) \
        int t0 = ((int)__float_as_uint(d20.x)) >> 20; \
        int t1 = ((int)__float_as_uint(d20.y)) >> 20; \
        int t2 = ((int)__float_as_uint(d21.x)) >> 20; \
        int t3 = ((int)__float_as_uint(d21.y)) >> 20; \
        int m30 = min(max(t0, 960), 1088); \
        int m31 = min(max(t1, 960), 1088); \
        int m32 = min(max(t2, 960), 1088); \
        int m33 = min(max(t3, 960), 1088); \
        atomicAdd(&hist[m30 * 64 + laneAdj], 1u); \
        atomicAdd(&hist[m31 * 64 + laneAdj], 1u); \
        atomicAdd(&hist[m32 * 64 + laneAdj], 1u); \
        atomicAdd(&hist[m33 * 64 + laneAdj], 1u); \
    } while (0)

    // ---- pass 1: histogram; manual 2-stage VMEM pipeline (even/odd bodies).
    // Final prefetch reads 64 B past this wave's chunk: still inside the
    // workspace (next wave's chunk / next batch / vfeat region) -> safe.
    {
        v4f a0, a1, a2, a3, b0, b1, b2, b3;
        LOADG(a0, a1, a2, a3, 0);
        #pragma unroll 1
        for (int it = 0; it < 64; ++it) {
            LOADG(b0, b1, b2, b3, (2 * it + 1) * 64);
            P1BODY(a0, a1, a2, a3);
            LOADG(a0, a1, a2, a3, (2 * it + 2) * 64);
            P1BODY(b0, b1, b2, b3);
        }
    }
    __syncthreads();

    // ---- find crossing bin (threads 0..63, one query each) ----
    if (threadIdx.x < 64) {
        int cum = 0, Bq = 128, cl = 0;
        for (int b2 = 0; b2 < NBIN; ++b2) {
            int c = (int)hist[b2 * 64 + threadIdx.x];
            if (cum + c >= KK) { Bq = b2; cl = cum; break; }
            cum += c;
        }
        binB[threadIdx.x] = Bq;
        cumLoA[threadIdx.x] = cl;
    }
    __syncthreads();

    // ---- per-lane BITS-domain thresholds for pass 2 ----
    // relevant (bin <= Bq) <=> bits <= THb;  within that: direct <=> bits < TLb
    const int Bq = binB[lane];
    const int TLb = (Bq > 0)    ? ((960 + Bq) << 20) : INT_MIN;
    const int THb = (Bq == 128) ? INT_MAX : (((960 + Bq + 1) << 20) - 1);
    const int grow = batch * NN + q;
    const int gBase = batch * NN;

    // buf[pos][lane] (transposed): 64 pos x 64 lanes x 8B = 32 KB (inside hist)
    unsigned long long* buf = (unsigned long long*)hist;

#define EMIT(Bx, jj) do { \
        if ((Bx) <= THb) {                       /* rare (~1% of candidates) */ \
            if ((Bx) < TLb) { \
                uint32_t pos = atomicAdd(&dirCnt[lane], 1u); \
                idx_ws[grow * KK + (int)pos] = gBase + (jj); \
            } else { \
                uint32_t db = (uint32_t)max((Bx), 0);        /* exact key */ \
                uint32_t pos = atomicAdd(&bufCnt[lane], 1u); \
                if (pos < 64u) buf[(int)pos * 64 + lane] = \
                    ((unsigned long long)db << 32) | (uint32_t)(jj); \
            } \
        } } while (0)

#define P2BODY(A0, A1, A2, A3, jb) do { \
        DISTS(A0, A1, A2, A3) \
        int B0 = (int)__float_as_uint(d20.x); \
        int B1 = (int)__float_as_uint(d20.y); \
        int B2 = (int)__float_as_uint(d21.x); \
        int B3 = (int)__float_as_uint(d21.y); \
        EMIT(B0, (jb) + 0); \
        EMIT(B1, (jb) + 1); \
        EMIT(B2, (jb) + 2); \
        EMIT(B3, (jb) + 3); \
    } while (0)

    // ---- pass 2: one-compare hot path; same VMEM pipeline ----
    {
        const int j0 = 2 * h0;
        v4f a0, a1, a2, a3, b0, b1, b2, b3;
        LOADG(a0, a1, a2, a3, 0);
        #pragma unroll 1
        for (int it = 0; it < 64; ++it) {
            LOADG(b0, b1, b2, b3, (2 * it + 1) * 64);
            P2BODY(a0, a1, a2, a3, j0 + 8 * it);
            LOADG(a0, a1, a2, a3, (2 * it + 2) * 64);
            P2BODY(b0, b1, b2, b3, j0 + 8 * it + 4);
        }
    }
    __syncthreads();

#undef LOADG
#undef DISTS
#undef P1BODY
#undef P2BODY
#undef EMIT

    // ---- final: pick (36 - cumLo) smallest exact keys from boundary bin ----
    if (threadIdx.x < 64) {
        const int t = threadIdx.x;
        const int q2 = qbase + t;
        const int grow2 = batch * NN + q2;
        const int cl = cumLoA[t];
        const int r = KK - cl;
        const int M = min((int)bufCnt[t], 64);
        const int outp = grow2 * KK + cl;
        for (int i = 0; i < r; ++i) {
            unsigned long long best = ~0ULL; int bi = -1;
            for (int u = 0; u < M; ++u) {
                unsigned long long v = buf[u * 64 + t];
                if (v < best) { best = v; bi = u; }
            }
            int jj;
            if (bi >= 0) { buf[bi * 64 + t] = ~0ULL; jj = (int)(best & 0xFFFFFFFFu); }
            else jj = q2;                            // pathological fallback
            if (jj < 0 || jj >= NN) jj = q2;
            idx_ws[outp + i] = batch * NN + jj;
        }
    }
}

// ---------------------------------------------------------------------------
// Kernel 3: attention + projection (best-measured form). LDS only for
// G staging, two half-channel rounds G[4][36][33] (~19 KB -> 8 blocks/CU).
// F from SGPRs; softmax via DPP (VALU); weights/projection via v_readlane.
// grid = NPTS/4 blocks of 256, one point per wave. No __syncthreads.
// ---------------------------------------------------------------------------
#define IDX(k) ((((k) & 3) == 0 ? I[(k) >> 2].x : ((k) & 3) == 1 ? I[(k) >> 2].y : \
                 ((k) & 3) == 2 ? I[(k) >> 2].z : I[(k) >> 2].w) & (NPTS - 1))

__global__ __launch_bounds__(256) void k_att(
    const float* __restrict__ feat, const float* __restrict__ vfeat,
    const int* __restrict__ idxw, const float* __restrict__ Wsuf,
    const float* __restrict__ bsuf, float* __restrict__ out)
{
    __shared__ float G[4][KK][33];   // 19,008 B (stride 33 == 1 mod 32: <=2-way)
    const int lane = laneid();
    const int wv = waveid_uniform();
    const int p = blockIdx.x * 4 + wv;

    // preload all 36 neighbor indices (wave-uniform s_load)
    const int4* __restrict__ myidx4 = (const int4*)(idxw + p * KK);
    int4 I[9];
    #pragma unroll
    for (int t = 0; t < 9; ++t) I[t] = myidx4[t];

    const float* __restrict__ Fp = feat + (size_t)p * CC;  // uniform -> s_load

    const int half = lane >> 5;       // 0: rows 2kk, 1: rows 2kk+1
    const int cpart = lane & 31;      // column within the 32-wide half

    float a = 0.0f;
    #pragma unroll
    for (int h = 0; h < 2; ++h) {
        // stage half h: 18 wave-loads, each covering two rows' 32-col halves
        #pragma unroll
        for (int kk = 0; kk < 18; ++kk) {
            int jrow = half ? IDX(2 * kk + 1) : IDX(2 * kk);
            G[wv][2 * kk + half][cpart] = feat[(size_t)jrow * CC + h * 32 + cpart];
        }
        // partial logits over this channel half (lane = k < 36); F is scalar
        if (lane < KK) {
            #pragma unroll 8
            for (int c = 0; c < 32; ++c)
                a = fmaf(Fp[h * 32 + c], G[wv][lane][c], a);
        }
    }
    const float logit = (lane < KK) ? a : -1e30f;

    // softmax across the 36 logit lanes — DPP (VALU pipe), no LDS
    const float m = wave_max_dpp(logit);
    const float e = (lane < KK) ? __expf(logit - m) : 0.0f;
    const float s = wave_sum_dpp(e);
    const float w = e * __frcp_rn(s);            // per-lane weight (0 for >=36)

    // weighted V gather: lane = channel; weight broadcast via v_readlane
    float acc = 0.0f;
    #pragma unroll
    for (int k = 0; k < KK; ++k) {
        float wk = rdlane_f(w, k);
        int j = IDX(k);
        acc = fmaf(wk, vfeat[j * OUTD + lane], acc);
    }

    // projection: o[lane] = b[lane] + sum_c acc_c * Wsuf[c][lane]
    float o = bsuf[lane];
    #pragma unroll 8
    for (int c = 0; c < OUTD; ++c) {
        float ac = rdlane_f(acc, c);
        o = fmaf(ac, Wsuf[c * OUTD + lane], o);
    }
    out[(size_t)p * OUTD + lane] = o;

    if (p == 0 && lane == 0) out[(size_t)NPTS * OUTD] = (float)NN;  // scalar N
}

// ---------------------------------------------------------------------------
extern "C" void kernel_launch(void* const* d_in, const int* in_sizes, int n_in,
                              void* d_out, int out_size, void* d_ws, size_t ws_size,
                              hipStream_t stream)
{
    const float* feat = (const float*)d_in[0];
    const float* xyz  = (const float*)d_in[1];
    const float* Wv   = (const float*)d_in[2];
    const float* bv   = (const float*)d_in[3];
    const float* Wsuf = (const float*)d_in[4];
    const float* bsuf = (const float*)d_in[5];
    float* out = (float*)d_out;

    char* ws = (char*)d_ws;
    float* xp = (float*)ws;                                   // 512 KB interleaved
    float*  vfeat = (float*)(ws + (512 << 10));               // 8 MB
    int*    idxw  = (int*)(ws + (512 << 10) + (8 << 20));     // 4.5 MB

    k_vfeat<<<NPTS / 32, 256, 0, stream>>>(feat, xyz, Wv, bv, vfeat, xp);
    k_knn  <<<NPTS / 64, 1024, 0, stream>>>(xp, idxw);
    k_att  <<<NPTS / 4, 256, 0, stream>>>(feat, vfeat, idxw, Wsuf, bsuf, out);
}

// Round 2
// 242.737 us; speedup vs baseline: 1.5350x; 1.5350x over previous
//
#include <hip/hip_runtime.h>
#include <stdint.h>
#include <limits.h>

// Problem constants (reference: B=4, N=8192, C=64, OUT=64, KNN=36)
#define BB 4
#define NN 8192
#define CC 64
#define OUTD 64
#define KK 36
#define NPTS (BB * NN)          // 32768
#define NBIN 129                // bins 0..128 (0 and 128 are clamp catch-alls)
// t = signed(float_bits(d2)) >> 20 (arith); bin = med3_i32(t,960,1088) - 960.
// Negative d2 (fp rounding) -> t very negative -> bin 0. One integer t per bin.
//
// xyzw layout: PAIR-INTERLEAVED. For even j: 8 floats
//   [x_j, x_j1, y_j, y_j1, z_j, z_j1, w_j, w_j1]   (j1 = j+1; 32 B per pair)
// -> wave-uniform s_load_dwordx16 batches (VALIDATED fast in R0; the R1 VMEM
//    broadcast experiment regressed 1.9x - scalar path is the right fetch).

typedef float v2f __attribute__((ext_vector_type(2)));

static __device__ __forceinline__ int laneid() { return threadIdx.x & 63; }
static __device__ __forceinline__ int waveid_uniform() {
    return __builtin_amdgcn_readfirstlane((int)(threadIdx.x >> 6));
}
static __device__ __forceinline__ float rdlane_f(float v, int l) {
    return __int_as_float(__builtin_amdgcn_readlane(__float_as_int(v), l));
}
static __device__ __forceinline__ unsigned long long shflx_ull(
        unsigned long long v, int m) {
    uint32_t lo = (uint32_t)v, hi = (uint32_t)(v >> 32);
    lo = (uint32_t)__shfl_xor((int)lo, m, 64);
    hi = (uint32_t)__shfl_xor((int)hi, m, 64);
    return ((unsigned long long)hi << 32) | lo;
}
// DPP helper: VALU-pipe cross-lane (no LDS). ctrl/bound must be constants.
#define DPP_F(oldv, v, ctrl, bound) \
    __int_as_float(__builtin_amdgcn_update_dpp( \
        __float_as_int(oldv), __float_as_int(v), (ctrl), 0xf, 0xf, (bound)))

// 64-lane sum: result in lane 63 (row_shr prefix + row_bcast combine)
static __device__ __forceinline__ float wave_sum_dpp(float v) {
    v += DPP_F(0.0f, v, 0x111, true);   // row_shr:1
    v += DPP_F(0.0f, v, 0x112, true);   // row_shr:2
    v += DPP_F(0.0f, v, 0x114, true);   // row_shr:4
    v += DPP_F(0.0f, v, 0x118, true);   // row_shr:8
    v += DPP_F(0.0f, v, 0x142, true);   // row_bcast:15
    v += DPP_F(0.0f, v, 0x143, true);   // row_bcast:31
    return rdlane_f(v, 63);
}
// 64-lane max: OOB lanes keep old=v (no-op under max)
static __device__ __forceinline__ float wave_max_dpp(float v) {
    v = fmaxf(v, DPP_F(v, v, 0x111, false));
    v = fmaxf(v, DPP_F(v, v, 0x112, false));
    v = fmaxf(v, DPP_F(v, v, 0x114, false));
    v = fmaxf(v, DPP_F(v, v, 0x118, false));
    v = fmaxf(v, DPP_F(v, v, 0x142, false));
    v = fmaxf(v, DPP_F(v, v, 0x143, false));
    return rdlane_f(v, 63);
}

// ---------------------------------------------------------------------------
// Kernel 1: v_feat = relu([feature, xyz] @ W_v + b_v)  + pair-interleaved xyzw.
// One wave handles 8 points. Block = 256 = 4 waves. grid = NPTS/32.
// ---------------------------------------------------------------------------
__global__ __launch_bounds__(256) void k_vfeat(
    const float* __restrict__ feat, const float* __restrict__ xyz,
    const float* __restrict__ Wv, const float* __restrict__ bv,
    float* __restrict__ vfeat, float* __restrict__ xp)   // xp: interleaved xyzw
{
    __shared__ float fb[4][8][64];
    __shared__ float xb[4][8][3];
    const int lane = laneid();
    const int wv = waveid_uniform();
    const int pbase = blockIdx.x * 32 + wv * 8;

    #pragma unroll
    for (int pp = 0; pp < 8; ++pp)
        fb[wv][pp][lane] = feat[(pbase + pp) * CC + lane];
    if (lane < 24)
        xb[wv][lane / 3][lane % 3] = xyz[pbase * 3 + lane];
    // same-wave LDS write->read: in-order per wave, compiler inserts lgkmcnt

    const float b0 = bv[lane];
    float acc[8];
    #pragma unroll
    for (int pp = 0; pp < 8; ++pp) acc[pp] = b0;

    #pragma unroll 4
    for (int c = 0; c < CC; ++c) {
        float w = Wv[c * OUTD + lane];
        #pragma unroll
        for (int pp = 0; pp < 8; ++pp)
            acc[pp] = fmaf(fb[wv][pp][c], w, acc[pp]);
    }
    const float wx = Wv[64 * OUTD + lane];
    const float wy = Wv[65 * OUTD + lane];
    const float wz = Wv[66 * OUTD + lane];
    #pragma unroll
    for (int pp = 0; pp < 8; ++pp) {
        float a = acc[pp];
        a = fmaf(xb[wv][pp][0], wx, a);
        a = fmaf(xb[wv][pp][1], wy, a);
        a = fmaf(xb[wv][pp][2], wz, a);
        vfeat[(pbase + pp) * OUTD + lane] = fmaxf(a, 0.0f);
    }
    if (lane < 8) {
        const int p = pbase + lane;
        const float x = xb[wv][lane][0], y = xb[wv][lane][1], z = xb[wv][lane][2];
        const float sq = (x * x + y * y) + z * z;
        const int base = (p >> 1) * 8 + (p & 1);    // pair-interleaved slot
        xp[base + 0] = x;
        xp[base + 2] = y;
        xp[base + 4] = z;
        xp[base + 6] = sq;
    }
}

// ---------------------------------------------------------------------------
// Kernel 2: 36-NN via per-query float-bit histogram selection.
// 512 blocks x 1024 thr, 64 queries/block (lane-per-query), 2 blocks/CU.
//
// V3 structure (reverted to validated SMEM fetch + two targeted fixes):
//  (a) explicit ping-pong SGPR double-buffer of 4-pair candidate sets
//      (2x s_load_dwordx16 per set): the lgkmcnt(0) drain that consumes a
//      set now lands ~44 VALU cycles after its loads were issued, and the
//      ds_add atomic queue is drained once per 8 candidates, not per 4.
//  (b) final boundary-bin selection parallelized across all 16 waves
//      (wave w owns queries 4w..4w+3; one shfl_xor 64-bit min-reduce per
//      pick) instead of 1 wave doing divergent r x M serial LDS scans.
//      Boundary keys live in buf2[64][65] (row per query, stride-65 ull).
//
// Pass 2 thresholds in BITS domain (validated correct in R1 run):
//   bin <= Bq  <=>  bits <= ((960+Bq+1)<<20)-1 ;  direct <=> bits < (960+Bq)<<20
//   exact key  fmaxf(d,0) bits == max(bits,0).
// Tie-break matches lax.top_k: (distance-bits, then smaller index).
// ---------------------------------------------------------------------------
__global__ __launch_bounds__(1024, 8) void k_knn(
    const float* __restrict__ xpAll, int* __restrict__ idx_ws)
{
    __shared__ __align__(16) uint32_t hist[NBIN * 64];          // 33.0 KB
    __shared__ __align__(16) unsigned long long buf2[64][65];   // 33.3 KB
    __shared__ int binB[64];
    __shared__ int cumLoA[64];
    __shared__ uint32_t bufCnt[64];
    __shared__ uint32_t dirCnt[64];

    const int lane = laneid();
    const int wv = waveid_uniform();               // 0..15
    const int batch = blockIdx.x >> 7;             // 128 blocks per batch
    const int qbase = (blockIdx.x & 127) << 6;
    const int q = qbase + lane;                    // local query id 0..8191
    const float* __restrict__ xp = xpAll + (size_t)batch * NN * 4;
    const v2f* __restrict__ X2 = (const v2f*)xp;   // pair h -> X2[4h..4h+3]

    // per-lane query fetch from the interleaved layout (once per block)
    const int pr = q >> 1, sub0 = q & 1;
    const float Qx = xp[pr * 8 + sub0 + 0];
    const float Qy = xp[pr * 8 + sub0 + 2];
    const float Qz = xp[pr * 8 + sub0 + 4];
    const float Qw = xp[pr * 8 + sub0 + 6];
    const v2f qx = { Qx, Qx };
    const v2f qy = { Qy, Qy };
    const v2f qz = { Qz, Qz };
    const v2f qw = { Qw, Qw };
    const v2f m2 = { -2.0f, -2.0f };

    const int h0 = wv * 256;                       // pair-index base (512 cands)
    const int laneAdj = lane - 960 * 64;           // fold bin rebase into addressing

    for (int i = threadIdx.x; i < NBIN * 64; i += 1024) hist[i] = 0u;
    if (threadIdx.x < 64) { bufCnt[threadIdx.x] = 0u; dirCnt[threadIdx.x] = 0u; }
    __syncthreads();

// one set = 4 pairs = 8 candidates = 128 B = 2x s_load_dwordx16 (wave-uniform)
#define LOADSET(S, si) do { \
        const v2f* _p = X2 + 4 * (h0 + 4 * (si)); \
        _Pragma("unroll") \
        for (int _k = 0; _k < 16; ++_k) (S)[_k] = _p[_k]; } while (0)

// distance math for pair j of a set (identical op sequence in both passes
// -> identical bits -> histogram/selection consistency)
#define PAIRD2(S, j, d2) \
        v2f _dot = __builtin_elementwise_fma(qx, (S)[4*(j)+0], \
                   __builtin_elementwise_fma(qy, (S)[4*(j)+1], \
                                             qz * (S)[4*(j)+2])); \
        v2f d2   = __builtin_elementwise_fma(m2, _dot, qw + (S)[4*(j)+3]);

#define P1SET(S) do { \
        _Pragma("unroll") \
        for (int _j = 0; _j < 4; ++_j) { \
            PAIRD2(S, _j, _d2) \
            int _t0 = ((int)__float_as_uint(_d2.x)) >> 20; \
            int _t1 = ((int)__float_as_uint(_d2.y)) >> 20; \
            int _b0 = min(max(_t0, 960), 1088);            /* v_med3_i32 */ \
            int _b1 = min(max(_t1, 960), 1088); \
            atomicAdd(&hist[_b0 * 64 + laneAdj], 1u); \
            atomicAdd(&hist[_b1 * 64 + laneAdj], 1u); \
        } } while (0)

    // ---- pass 1: histogram; ping-pong prefetch (sets 0..63; prefetch of
    // set 64 overruns this wave's chunk by 128 B -> still inside the
    // workspace (next chunk / next batch / vfeat region) -> safe.
    {
        v2f A[16], Bv[16];
        LOADSET(A, 0);
        #pragma unroll 1
        for (int it = 0; it < 32; ++it) {
            LOADSET(Bv, 2 * it + 1);
            P1SET(A);
            LOADSET(A, 2 * it + 2);
            P1SET(Bv);
        }
    }
    __syncthreads();

    // ---- find crossing bin (threads 0..63, one query each) ----
    if (threadIdx.x < 64) {
        int cum = 0, Bq = 128, cl = 0;
        for (int b2 = 0; b2 < NBIN; ++b2) {
            int c = (int)hist[b2 * 64 + threadIdx.x];
            if (cum + c >= KK) { Bq = b2; cl = cum; break; }
            cum += c;
        }
        binB[threadIdx.x] = Bq;
        cumLoA[threadIdx.x] = cl;
    }
    __syncthreads();

    // ---- per-lane BITS-domain thresholds for pass 2 ----
    const int Bq = binB[lane];
    const int TLb = (Bq > 0)    ? ((960 + Bq) << 20) : INT_MIN;
    const int THb = (Bq == 128) ? INT_MAX : (((960 + Bq + 1) << 20) - 1);
    const int grow = batch * NN + q;
    const int gBase = batch * NN;

#define EMIT(Bx, jj) do { \
        if ((Bx) <= THb) {                       /* rare (~1% of candidates) */ \
            if ((Bx) < TLb) { \
                uint32_t pos = atomicAdd(&dirCnt[lane], 1u); \
                idx_ws[grow * KK + (int)pos] = gBase + (jj); \
            } else { \
                uint32_t db = (uint32_t)max((Bx), 0);        /* exact key */ \
                uint32_t pos = atomicAdd(&bufCnt[lane], 1u); \
                if (pos < 64u) buf2[lane][(int)pos] = \
                    ((unsigned long long)db << 32) | (uint32_t)(jj); \
            } \
        } } while (0)

#define P2SET(S, si) do { \
        _Pragma("unroll") \
        for (int _j = 0; _j < 4; ++_j) { \
            PAIRD2(S, _j, _d2) \
            int _B0 = (int)__float_as_uint(_d2.x); \
            int _B1 = (int)__float_as_uint(_d2.y); \
            const int _jb = 2 * (h0 + 4 * (si) + _j); \
            EMIT(_B0, _jb + 0); \
            EMIT(_B1, _jb + 1); \
        } } while (0)

    // ---- pass 2: one-compare hot path; same ping-pong pipeline ----
    {
        v2f A[16], Bv[16];
        LOADSET(A, 0);
        #pragma unroll 1
        for (int it = 0; it < 32; ++it) {
            LOADSET(Bv, 2 * it + 1);
            P2SET(A, 2 * it);
            LOADSET(A, 2 * it + 2);
            P2SET(Bv, 2 * it + 1);
        }
    }
    __syncthreads();

#undef LOADSET
#undef PAIRD2
#undef P1SET
#undef P2SET
#undef EMIT

    // ---- final: pick (36 - cumLo) smallest exact keys from boundary bin.
    // Parallel across all 16 waves: wave wv owns queries 4wv..4wv+3; keys
    // one-per-lane; each pick is a 6-step shfl_xor 64-bit min-reduce.
    // Keys are unique (low 32 bits = candidate index) -> unique argmin.
    #pragma unroll 1
    for (int sub = 0; sub < 4; ++sub) {
        const int t = 4 * wv + sub;                 // wave-uniform query slot
        const int cl = cumLoA[t];
        const int r = KK - cl;                      // >= 1 always
        const int M = min((int)bufCnt[t], 64);
        const int q2 = qbase + t;
        const int outp = (batch * NN + q2) * KK + cl;
        unsigned long long key = (lane < M) ? buf2[t][lane] : ~0ULL;
        #pragma unroll 1
        for (int i = 0; i < r; ++i) {
            unsigned long long mk = key;
            #pragma unroll
            for (int d = 32; d >= 1; d >>= 1) {
                unsigned long long o = shflx_ull(mk, d);
                mk = (o < mk) ? o : mk;
            }
            int jj = (mk == ~0ULL) ? q2 : (int)(uint32_t)(mk & 0xFFFFFFFFu);
            if (jj < 0 || jj >= NN) jj = q2;         // pathological fallback
            if (lane == 0) idx_ws[outp + i] = batch * NN + jj;
            if (key == mk) key = ~0ULL;              // retire the winner
        }
    }
}

// ---------------------------------------------------------------------------
// Kernel 3: attention + projection (best-measured form). LDS only for
// G staging, two half-channel rounds G[4][36][33] (~19 KB -> 8 blocks/CU).
// F from SGPRs; softmax via DPP (VALU); weights/projection via v_readlane.
// grid = NPTS/4 blocks of 256, one point per wave. No __syncthreads.
// ---------------------------------------------------------------------------
#define IDX(k) ((((k) & 3) == 0 ? I[(k) >> 2].x : ((k) & 3) == 1 ? I[(k) >> 2].y : \
                 ((k) & 3) == 2 ? I[(k) >> 2].z : I[(k) >> 2].w) & (NPTS - 1))

__global__ __launch_bounds__(256) void k_att(
    const float* __restrict__ feat, const float* __restrict__ vfeat,
    const int* __restrict__ idxw, const float* __restrict__ Wsuf,
    const float* __restrict__ bsuf, float* __restrict__ out)
{
    __shared__ float G[4][KK][33];   // 19,008 B (stride 33 == 1 mod 32: <=2-way)
    const int lane = laneid();
    const int wv = waveid_uniform();
    const int p = blockIdx.x * 4 + wv;

    // preload all 36 neighbor indices (wave-uniform s_load)
    const int4* __restrict__ myidx4 = (const int4*)(idxw + p * KK);
    int4 I[9];
    #pragma unroll
    for (int t = 0; t < 9; ++t) I[t] = myidx4[t];

    const float* __restrict__ Fp = feat + (size_t)p * CC;  // uniform -> s_load

    const int half = lane >> 5;       // 0: rows 2kk, 1: rows 2kk+1
    const int cpart = lane & 31;      // column within the 32-wide half

    float a = 0.0f;
    #pragma unroll
    for (int h = 0; h < 2; ++h) {
        // stage half h: 18 wave-loads, each covering two rows' 32-col halves
        #pragma unroll
        for (int kk = 0; kk < 18; ++kk) {
            int jrow = half ? IDX(2 * kk + 1) : IDX(2 * kk);
            G[wv][2 * kk + half][cpart] = feat[(size_t)jrow * CC + h * 32 + cpart];
        }
        // partial logits over this channel half (lane = k < 36); F is scalar
        if (lane < KK) {
            #pragma unroll 8
            for (int c = 0; c < 32; ++c)
                a = fmaf(Fp[h * 32 + c], G[wv][lane][c], a);
        }
    }
    const float logit = (lane < KK) ? a : -1e30f;

    // softmax across the 36 logit lanes — DPP (VALU pipe), no LDS
    const float m = wave_max_dpp(logit);
    const float e = (lane < KK) ? __expf(logit - m) : 0.0f;
    const float s = wave_sum_dpp(e);
    const float w = e * __frcp_rn(s);            // per-lane weight (0 for >=36)

    // weighted V gather: lane = channel; weight broadcast via v_readlane
    float acc = 0.0f;
    #pragma unroll
    for (int k = 0; k < KK; ++k) {
        float wk = rdlane_f(w, k);
        int j = IDX(k);
        acc = fmaf(wk, vfeat[j * OUTD + lane], acc);
    }

    // projection: o[lane] = b[lane] + sum_c acc_c * Wsuf[c][lane]
    float o = bsuf[lane];
    #pragma unroll 8
    for (int c = 0; c < OUTD; ++c) {
        float ac = rdlane_f(acc, c);
        o = fmaf(ac, Wsuf[c * OUTD + lane], o);
    }
    out[(size_t)p * OUTD + lane] = o;

    if (p == 0 && lane == 0) out[(size_t)NPTS * OUTD] = (float)NN;  // scalar N
}

// ---------------------------------------------------------------------------
extern "C" void kernel_launch(void* const* d_in, const int* in_sizes, int n_in,
                              void* d_out, int out_size, void* d_ws, size_t ws_size,
                              hipStream_t stream)
{
    const float* feat = (const float*)d_in[0];
    const float* xyz  = (const float*)d_in[1];
    const float* Wv   = (const float*)d_in[2];
    const float* bv   = (const float*)d_in[3];
    const float* Wsuf = (const float*)d_in[4];
    const float* bsuf = (const float*)d_in[5];
    float* out = (float*)d_out;

    char* ws = (char*)d_ws;
    float* xp = (float*)ws;                                   // 512 KB interleaved
    float*  vfeat = (float*)(ws + (512 << 10));               // 8 MB
    int*    idxw  = (int*)(ws + (512 << 10) + (8 << 20));     // 4.5 MB

    k_vfeat<<<NPTS / 32, 256, 0, stream>>>(feat, xyz, Wv, bv, vfeat, xp);
    k_knn  <<<NPTS / 64, 1024, 0, stream>>>(xp, idxw);
    k_att  <<<NPTS / 4, 256, 0, stream>>>(feat, vfeat, idxw, Wsuf, bsuf, out);
}